// Round 8
// baseline (158.099 us; speedup 1.0000x reference)
//
#include <hip/hip_runtime.h>
#include <hip/hip_bf16.h>
#include <stdint.h>

typedef __attribute__((ext_vector_type(8))) short bf16x8;  // 8 bf16 (4 VGPRs)
typedef __attribute__((ext_vector_type(4))) short s16x4;   // 4 bf16 (8B store)
typedef __attribute__((ext_vector_type(4))) float f32x4;   // 4 f32 acc

#define RD 1024
#define LD 112
#define SCALE_C 2.8853900817779268f   // 2/ln2: tanh(z) = 1 - 2/(1+2^(C*z))
#define CHK 64                        // k per LDS chunk in fence_out
#define NCHK (RD/CHK)                 // 16 chunks
#define NB_PT2 448                    // 448*256 = LD*RD elements
// flat LDS chunk buffer layout (bytes): Pt2 14 KB | E 4 KB | F 2 KB = 20 KB
#define OFF_E 14336
#define OFF_F 18432

static __device__ __forceinline__ unsigned pkbf(float lo, float hi){
  return __builtin_amdgcn_perm(__builtin_bit_cast(unsigned, hi),
                               __builtin_bit_cast(unsigned, lo), 0x07060302u);
}
static __device__ __forceinline__ float exp2_f(float t){
#if __has_builtin(__builtin_amdgcn_exp2f)
  return __builtin_amdgcn_exp2f(t);
#else
  return exp2f(t);
#endif
}
static __device__ __forceinline__ float rcp_f(float t){
#if __has_builtin(__builtin_amdgcn_rcpf)
  return __builtin_amdgcn_rcpf(t);
#else
  return 1.0f / t;
#endif
}
static __device__ __forceinline__ short f2bf_rn(float f){
  unsigned u = __builtin_bit_cast(unsigned, f);
  return (short)((u + 0x7fffu + ((u >> 16) & 1u)) >> 16);
}
typedef const __attribute__((address_space(1))) unsigned int* gas1;
typedef __attribute__((address_space(3))) unsigned int* las3;
static __device__ __forceinline__ void g2lds16(const void* g, void* l){
  __builtin_amdgcn_global_load_lds((gas1)g, (las3)l, 16, 0, 0);
}

// ---- fence_prep: fpb/Wb bf16 conversion only, float4-vectorized (4 elems/
//      thread, 6256 -> 1424 blocks; prep was scalar-load + launch bound).
//      Pt2/SB moved into fence_y's dispatch (they don't depend on prep). ----
__global__ __launch_bounds__(256)
void fence_prep(const float* __restrict__ x, const float* __restrict__ W,
                short* __restrict__ fpb, short* __restrict__ Wb, int ntok){
  int id4 = blockIdx.x*256 + threadIdx.x;
  int nfp4 = ntok * (RD/4);
  if (id4 < nfp4){
    int id = id4*4;
    int tok = id >> 10, d = id & (RD - 1);
    float4 v = {0.0f, 0.0f, 0.0f, 0.0f};
    if (tok < ntok - 1){
      if (d < RD/2) v = *(const float4*)(x + (size_t)tok*RD + d);
      else {
        float4 w = *(const float4*)(x + (size_t)(tok+1)*RD + d);
        v = (float4){-w.x, -w.y, -w.z, -w.w};
      }
    }
    s16x4 o = {f2bf_rn(v.x), f2bf_rn(v.y), f2bf_rn(v.z), f2bf_rn(v.w)};
    *(s16x4*)(fpb + id) = o;
  } else if (id4 < nfp4 + (RD*RD/4)){
    int p = (id4 - nfp4)*4;
    float4 w = *(const float4*)(W + p);
    s16x4 o = {f2bf_rn(w.x), f2bf_rn(w.y), f2bf_rn(w.z), f2bf_rn(w.w)};
    *(s16x4*)(Wb + p) = o;
  }
}

// ---- fence_y: blocks [0,nby): y = fp*W^T (bf16 MFMA); epilogue
//      E=2^(C(y+b)), F=2^(-Cy). Blocks [nby,nby+448): Pt2[l*RD+r] =
//      bf16(-2*P[r,l]). Blocks [nby+448,+112): SB[l] = sum_r P[r,l]+ob[l].
//      Pt2/SB depend only on P/ob, so they fill this dispatch's low-TLP
//      tail (y alone is 400 blocks = 1.6/CU) instead of serializing in
//      prep. ----
__global__ __launch_bounds__(256, 4)
void fence_y(const short* __restrict__ fpb, const short* __restrict__ Wb,
             const float* __restrict__ b, const float* __restrict__ P,
             const float* __restrict__ ob, short* __restrict__ Pt2,
             float* __restrict__ SB, float* __restrict__ E,
             float* __restrict__ F, int ntok, int nby){
  __shared__ float red[256];
  int blk = blockIdx.x, t = threadIdx.x;
  if (blk < nby){
    int wid  = blk*4 + (t >> 6);
    int lane = t & 63;
    int mt = wid >> 6;          // 0..24
    int ng = wid & 63;          // 0..63
    int lm = lane & 15, rq = lane >> 4;
    int arow = mt*16 + lm; if (arow > ntok - 1) arow = ntok - 1;
    const short* Ap = fpb + (size_t)arow*RD + rq*8;
    const short* Bp = Wb + (size_t)(ng*16 + lm)*RD + rq*8;
    f32x4 acc = {};
    #pragma unroll
    for (int kb = 0; kb < 32; ++kb){
      bf16x8 a = *(const bf16x8*)(Ap + kb*32);
      bf16x8 w = *(const bf16x8*)(Bp + kb*32);
      acc = __builtin_amdgcn_mfma_f32_16x16x32_bf16(a, w, acc, 0, 0, 0);
    }
    int r = ng*16 + lm;
    float bv = b[r];
    #pragma unroll
    for (int reg = 0; reg < 4; ++reg){
      int tt = mt*16 + rq*4 + reg;
      if (tt < ntok){
        float y = acc[reg];
        E[(size_t)tt*RD + r] = exp2_f(SCALE_C * (y + bv));
        F[(size_t)tt*RD + r] = exp2_f(-SCALE_C * y);
      }
    }
  } else if (blk < nby + NB_PT2){
    int id = (blk - nby)*256 + t;     // < LD*RD by exact sizing
    int l = id >> 10, rr = id & (RD - 1);
    Pt2[id] = f2bf_rn(-2.0f * P[rr*LD + l]);
  } else {
    int l = blk - nby - NB_PT2;       // 0..LD-1
    float s = 0.0f;
    for (int r = t; r < RD; r += 256) s += P[r*LD + l];
    red[t] = s; __syncthreads();
    for (int st = 128; st > 0; st >>= 1){
      if (t < st) red[t] += red[t + st];
      __syncthreads();
    }
    if (t == 0) SB[l] = red[0] + ob[l];
  }
}

// ---- fence_out: out[i,j,l] = SB[l] - 2*sum_r sigma*P[r,l], sigma=1/(1+E_j F_i).
//      R6/R7 structure (68.4-69.3 us; VGPR 60 + 56 AGPR acc, 40 KB LDS --
//      the verified occupancy sweet spot; E/F LDS-staged; T5 setprio +5.4%).
//      R8 change -- arithmetic only: PAIRWISE BATCHED RECIPROCAL. The 32
//      v_rcp_f32 per wave-chunk run on the quarter-rate trans pipe (~8 cy
//      each, ~33 us/CU total -- same order as the 41 us LDS floor). Pairing
//      r=rcp(a0*a1); s0=r*a1; s1=r*a0 halves rcp count at +3 cheap muls.
//      Safe: a = 1+E*F <= ~2^30 for this data (y~N(0,1)), no overflow; ~2ulp
//      added error << 0.03125 tolerance.
//      E chunk stored XOR-swizzled at float4 granularity (slot s of row r
//      holds global float4 s^r) so 16-row-stride reads are conflict-free. ----
__global__ __launch_bounds__(256, 4)
void fence_out(const float* __restrict__ E, const float* __restrict__ F,
               const short* __restrict__ Pt2, const float* __restrict__ SB,
               float* __restrict__ out, int nn, int njt){
  __shared__ __align__(16) char sbuf[2][20480];
  int wave = threadIdx.x >> 6, lane = threadIdx.x & 63;
  int lm = lane & 15, rq = lane >> 4;
  int it = blockIdx.x / njt, jt = blockIdx.x - it*njt;
  int ibase = it*8, jbase = jt*16;

  // per-wave stage descriptors: 5 x 1KB blocks each (20 total), precomputed
  const char* gp[5]; int lof[5]; int stp[5];
  #pragma unroll
  for (int s = 0; s < 5; ++s){
    int q = wave + s*4;
    if (q < 14){                       // Pt2: 14 blocks of (7 labels-of-16 x 2 kb)
      int kb = q / 7, g = q - kb*7;
      gp[s]  = (const char*)(Pt2 + (size_t)(g*16 + lm)*RD + kb*32 + rq*8);
      stp[s] = CHK*2;
      lof[s] = q*1024;
    } else if (q < 18){                // E: 4 blocks of 4 j-rows, XOR-swizzled src
      int ee = q - 14;
      int row = ee*4 + rq;             // 0..15
      int jr = jbase + row; if (jr > nn - 1) jr = nn - 1;
      int cb = lm ^ row;               // swizzle: slot lm holds float4 (lm^row)
      gp[s]  = (const char*)(E + (size_t)jr*RD + cb*4);
      stp[s] = CHK*4;
      lof[s] = OFF_E + ee*1024;
    } else {                           // F: 2 blocks of 4 i-rows, linear
      int ff = q - 18;
      int row = ff*4 + rq;             // 0..7
      int ir = ibase + row; if (ir > nn - 1) ir = nn - 1;
      gp[s]  = (const char*)(F + (size_t)ir*RD + lm*4);
      stp[s] = CHK*4;
      lof[s] = OFF_F + ff*1024;
    }
  }
  auto stage = [&](int c, int bi){
    #pragma unroll
    for (int s = 0; s < 5; ++s)
      g2lds16(gp[s] + (size_t)c*stp[s], &sbuf[bi][lof[s]]);
  };

  stage(0, 0);

  f32x4 acc[2][7];
  #pragma unroll
  for (int nt = 0; nt < 7; ++nt){
    float sv = SB[nt*16 + lm];
    acc[0][nt] = (f32x4){sv, sv, sv, sv};
    acc[1][nt] = (f32x4){sv, sv, sv, sv};
  }
  __syncthreads();

  for (int c = 0; c < NCHK; ++c){
    int bi = c & 1;
    if (c + 1 < NCHK) stage(c + 1, bi ^ 1);
    const short* pb = (const short*)&sbuf[bi][0];
    const float* eb = (const float*)&sbuf[bi][OFF_E];
    const float* fb = (const float*)&sbuf[bi][OFF_F];
    #pragma unroll
    for (int kb = 0; kb < 2; ++kb){
      int ko = kb*32 + rq*8;
      int cb0 = kb*8 + rq*2;
      float4 e0 = *(const float4*)(eb + lm*64 + ((cb0 ^ lm) * 4));
      float4 e1 = *(const float4*)(eb + lm*64 + (((cb0 + 1) ^ lm) * 4));
      bf16x8 af[2];
      #pragma unroll
      for (int u = 0; u < 2; ++u){
        const float* fr = fb + (wave*2 + u)*64 + ko;   // wave-uniform: broadcast
        float4 f0 = *(const float4*)fr;
        float4 f1 = *(const float4*)(fr + 4);
        // pairwise batched reciprocal: 4 rcp instead of 8
        float a0 = fmaf(e0.x, f0.x, 1.0f);
        float a1 = fmaf(e0.y, f0.y, 1.0f);
        float a2 = fmaf(e0.z, f0.z, 1.0f);
        float a3 = fmaf(e0.w, f0.w, 1.0f);
        float a4 = fmaf(e1.x, f1.x, 1.0f);
        float a5 = fmaf(e1.y, f1.y, 1.0f);
        float a6 = fmaf(e1.z, f1.z, 1.0f);
        float a7 = fmaf(e1.w, f1.w, 1.0f);
        float r01 = rcp_f(a0 * a1);
        float r23 = rcp_f(a2 * a3);
        float r45 = rcp_f(a4 * a5);
        float r67 = rcp_f(a6 * a7);
        float s0 = r01 * a1, s1 = r01 * a0;
        float s2 = r23 * a3, s3 = r23 * a2;
        float s4 = r45 * a5, s5 = r45 * a4;
        float s6 = r67 * a7, s7 = r67 * a6;
        union { unsigned u4[4]; bf16x8 v; } a;
        a.u4[0] = pkbf(s0, s1); a.u4[1] = pkbf(s2, s3);
        a.u4[2] = pkbf(s4, s5); a.u4[3] = pkbf(s6, s7);
        af[u] = a.v;
      }
      __builtin_amdgcn_s_setprio(1);   // T5: favor this wave through the MFMA burst
      #pragma unroll
      for (int nt = 0; nt < 7; ++nt){
        bf16x8 pf = *(const bf16x8*)(pb + (kb*7 + nt)*512 + lane*8);
        acc[0][nt] = __builtin_amdgcn_mfma_f32_16x16x32_bf16(af[0], pf, acc[0][nt], 0, 0, 0);
        acc[1][nt] = __builtin_amdgcn_mfma_f32_16x16x32_bf16(af[1], pf, acc[1][nt], 0, 0, 0);
      }
      __builtin_amdgcn_s_setprio(0);
    }
    __syncthreads();
  }

  // D layout: col=lm -> label, row=rq*4+reg -> j
  #pragma unroll
  for (int u = 0; u < 2; ++u){
    int i = ibase + wave*2 + u;
    if (i >= nn) continue;
    size_t dbase = (size_t)i * nn * LD;
    #pragma unroll
    for (int reg = 0; reg < 4; ++reg){
      int j = jbase + rq*4 + reg;
      if (j >= nn) continue;
      float* op = out + dbase + (size_t)j*LD + lm;
      #pragma unroll
      for (int nt = 0; nt < 7; ++nt) op[nt*16] = acc[u][nt][reg];
    }
  }
}

extern "C" void kernel_launch(void* const* d_in, const int* in_sizes, int n_in,
                              void* d_out, int out_size, void* d_ws, size_t ws_size,
                              hipStream_t stream){
  const float* x  = (const float*)d_in[0];
  const float* W  = (const float*)d_in[1];
  const float* b  = (const float*)d_in[2];
  const float* P  = (const float*)d_in[3];
  const float* ob = (const float*)d_in[4];
  int ntok = in_sizes[0] / RD;   // 400
  int nn = ntok - 1;             // 399

  char* ws = (char*)d_ws;
  size_t o_fpb = 0;
  size_t o_Wb  = o_fpb + (size_t)ntok*RD*2;
  size_t o_Pt2 = o_Wb  + (size_t)RD*RD*2;
  size_t o_E   = o_Pt2 + (size_t)LD*RD*2;
  size_t o_F   = o_E   + (size_t)ntok*RD*4;
  size_t o_SB  = o_F   + (size_t)ntok*RD*4;
  short* fpb = (short*)(ws + o_fpb);
  short* Wb  = (short*)(ws + o_Wb);
  short* Pt2 = (short*)(ws + o_Pt2);
  float* E   = (float*)(ws + o_E);
  float* F   = (float*)(ws + o_F);
  float* SB  = (float*)(ws + o_SB);

  int nfp4 = ntok*(RD/4);
  int nbp  = (nfp4 + (RD*RD/4) + 255)/256;   // 1424
  fence_prep<<<nbp, 256, 0, stream>>>(x, W, fpb, Wb, ntok);

  int mtiles = (ntok + 15) / 16;       // 25
  int nby = mtiles*16;                 // 400 y-blocks
  fence_y<<<nby + NB_PT2 + LD, 256, 0, stream>>>(fpb, Wb, b, P, ob, Pt2, SB, E, F, ntok, nby);

  int njt = (nn + 15) / 16;            // 25
  int nit = (nn + 7) / 8;              // 50
  fence_out<<<nit*njt, 256, 0, stream>>>(E, F, Pt2, SB, (float*)d_out, nn, njt);
}